// Round 2
// baseline (509.647 us; speedup 1.0000x reference)
//
#include <hip/hip_runtime.h>

#define S     4096
#define CIN   7
#define DM    512
#define KERN  73
#define TT    128          // time steps per block tile
#define TILES (S / TT)     // 32
#define NSTAGE (TT + 17)   // 145 valid staged elements per channel row
#define TROW  176          // row stride: covers refill reads up to j=159, 16B-aligned, 704B*? -> bank-safe
#define CHUNK 8

__global__ __launch_bounds__(512, 6)
void tokemb_kernel(const float* __restrict__ x,
                   const float* __restrict__ w_conv,
                   const float* __restrict__ b_conv,
                   const float* __restrict__ w_left,
                   const float* __restrict__ b_left,
                   float* __restrict__ out)
{
    __shared__ float xs[CIN * TROW];

    const int blk  = blockIdx.x;
    const int b    = blk / TILES;
    const int tile = blk - b * TILES;
    const int t0   = tile * TT;
    const int d    = threadIdx.x;

    // ---- stage x tile into LDS transposed: xs[c][j] = x[b, (t0-16+j) mod S, c]
    const float* xb = x + (long long)b * S * CIN;
    for (int e = d; e < CIN * NSTAGE; e += 512) {
        int j = e / CIN;
        int c = e - j * CIN;
        int tm = t0 - 16 + j;
        if (tm < 0) tm += S;
        else if (tm >= S) tm -= S;
        xs[c * TROW + j] = xb[tm * CIN + c];
    }

    // ---- per-thread weights (18 floats) ----
    const int cc = (d < DM - 1) ? (d / KERN) : (CIN - 1);
    const int oo = d % KERN;
    const float* wrow = (d < DM - 1) ? (w_conv + oo * 18) : w_left;
    const float bias  = (d < DM - 1) ? b_conv[oo] : b_left[0];
    float wt[18];
    #pragma unroll
    for (int q = 0; q < 18; ++q) wt[q] = wrow[q];

    __syncthreads();

    const float* xrow = xs + cc * TROW;
    float* op = out + ((long long)b * S + t0) * DM + d;

    // rolling window: buf[j & 31] holds xs[j]; prologue fills j in [0,32)
    float buf[32];
    #pragma unroll
    for (int q = 0; q < 8; ++q) {
        float4 v = *reinterpret_cast<const float4*>(xrow + 4 * q);
        buf[4*q+0] = v.x; buf[4*q+1] = v.y;
        buf[4*q+2] = v.z; buf[4*q+3] = v.w;
    }

    for (int B_ = 0; B_ < TT / 32; ++B_) {
        #pragma unroll
        for (int p = 0; p < 4; ++p) {
            const int tt0  = B_ * 32 + p * 8;
            const int base = p * 8;                 // tt0 & 31 (compile-time)
            const int tc   = t0 + tt0;

            float acc[CHUNK];
            const bool edge = (tc < 16) || (tc + CHUNK >= S);   // block-uniform
            if (!edge) {
                #pragma unroll
                for (int i = 0; i < CHUNK; ++i) {
                    float a = bias;
                    #pragma unroll
                    for (int m = 0; m < 6; ++m) {
                        #pragma unroll
                        for (int k = 0; k < 3; ++k) {
                            a = fmaf(wt[m*3+k], buf[(base + i + k + 15 - 3*m) & 31], a);
                        }
                    }
                    acc[i] = a;
                }
            } else {
                #pragma unroll
                for (int i = 0; i < CHUNK; ++i) {
                    float p0 = 0.f, p1 = 0.f, p2 = 0.f;
                    #pragma unroll
                    for (int m = 0; m < 6; ++m) {
                        p0 = fmaf(wt[m*3+0], buf[(base + i + 15 - 3*m) & 31], p0);
                        p1 = fmaf(wt[m*3+1], buf[(base + i + 16 - 3*m) & 31], p1);
                        p2 = fmaf(wt[m*3+2], buf[(base + i + 17 - 3*m) & 31], p2);
                    }
                    const int t = tc + i;
                    const float f0 = (t == 0 || t >= 16)     ? 1.f : 0.f;
                    const float f1 = (t >= 15)               ? 1.f : 0.f;
                    const float f2 = (t >= 14 && t != S - 1) ? 1.f : 0.f;
                    acc[i] = bias + f0 * p0 + f1 * p1 + f2 * p2;
                }
            }

            #pragma unroll
            for (int i = 0; i < CHUNK; ++i) {
                __builtin_nontemporal_store(acc[i], op + (tt0 + i) * DM);
            }

            // refill: j in [tt0+32, tt0+40) -> buf[base..base+7]
            // (last chunk reads stale LDS in [145,176) — values never used)
            float4 v0 = *reinterpret_cast<const float4*>(xrow + tt0 + 32);
            float4 v1 = *reinterpret_cast<const float4*>(xrow + tt0 + 36);
            buf[base+0] = v0.x; buf[base+1] = v0.y;
            buf[base+2] = v0.z; buf[base+3] = v0.w;
            buf[base+4] = v1.x; buf[base+5] = v1.y;
            buf[base+6] = v1.z; buf[base+7] = v1.w;
        }
    }
}

extern "C" void kernel_launch(void* const* d_in, const int* in_sizes, int n_in,
                              void* d_out, int out_size, void* d_ws, size_t ws_size,
                              hipStream_t stream) {
    const float* x      = (const float*)d_in[0];
    const float* w_conv = (const float*)d_in[1];
    const float* b_conv = (const float*)d_in[2];
    const float* w_left = (const float*)d_in[3];
    const float* b_left = (const float*)d_in[4];
    float* out = (float*)d_out;

    const int B = in_sizes[0] / (S * CIN);   // 32
    dim3 grid(B * TILES);
    tokemb_kernel<<<grid, 512, 0, stream>>>(x, w_conv, b_conv, w_left, b_left, out);
}

// Round 3
// 61.089 us; speedup vs baseline: 8.3427x; 8.3427x over previous
//
#include <hip/hip_runtime.h>

#define S     4096
#define CIN   7
#define DM    512
#define KERN  73
#define TT    128          // time steps per block tile
#define TILES (S / TT)     // 32
#define NSTAGE (TT + 17)   // 145 valid staged elements per channel row
#define TROW  148          // row stride in floats (16B-aligned)
#define CHUNK 8

// Interior chunk: 18-tap FIR on 8 consecutive t, tap-group order.
// xc = xs row + tt0 (16B aligned), opc = out + (t0+tt0)*DM + d.
// Stores are emitted as soon as each output's last tap lands (smooth issue).
__device__ __forceinline__ void do_chunk(const float* __restrict__ xc,
                                         const float g[18], float bias,
                                         float* __restrict__ opc)
{
    float acc[CHUNK];
    #pragma unroll
    for (int i = 0; i < CHUNK; ++i) acc[i] = bias;

    #pragma unroll
    for (int q = 0; q < 7; ++q) {
        float4 v = *reinterpret_cast<const float4*>(xc + 4 * q);
        float va[4] = {v.x, v.y, v.z, v.w};
        #pragma unroll
        for (int e = 0; e < 4; ++e) {
            const int j = 4 * q + e;           // window offset
            #pragma unroll
            for (int i = 0; i < CHUNK; ++i) {
                const int off = j - i;
                if (off >= 0 && off < 18)
                    acc[i] = fmaf(g[off], va[e], acc[i]);
            }
        }
        if (q == 4) {        // j<=19 done -> i=0..2 final (last tap j=i+17)
            #pragma unroll
            for (int i = 0; i <= 2; ++i) opc[i * DM] = acc[i];
        } else if (q == 5) { // j<=23 -> i=3..6 final
            #pragma unroll
            for (int i = 3; i <= 6; ++i) opc[i * DM] = acc[i];
        } else if (q == 6) { // i=7 final
            opc[7 * DM] = acc[7];
        }
    }
}

__global__ __launch_bounds__(512, 6)
void tokemb_kernel(const float* __restrict__ x,
                   const float* __restrict__ w_conv,
                   const float* __restrict__ b_conv,
                   const float* __restrict__ w_left,
                   const float* __restrict__ b_left,
                   float* __restrict__ out)
{
    __shared__ float xs[CIN * TROW];

    const int blk  = blockIdx.x;
    const int b    = blk / TILES;
    const int tile = blk - b * TILES;
    const int t0   = tile * TT;
    const int d    = threadIdx.x;

    // ---- stage x tile into LDS transposed: xs[c][j] = x[b, (t0-16+j) mod S, c]
    const float* xb = x + (long long)b * S * CIN;
    for (int e = d; e < CIN * NSTAGE; e += 512) {
        int j = e / CIN;
        int c = e - j * CIN;
        int tm = t0 - 16 + j;
        if (tm < 0) tm += S;
        else if (tm >= S) tm -= S;
        xs[c * TROW + j] = xb[tm * CIN + c];
    }

    // ---- per-thread weights, remapped to FIR tap order:
    // tap offset off = 15 - 3m + k  ->  g[off] = wrow[(5 - off/3)*3 + off%3]
    const int cc = (d < DM - 1) ? (d / KERN) : (CIN - 1);
    const int oo = d % KERN;
    const float* wrow = (d < DM - 1) ? (w_conv + oo * 18) : w_left;
    const float bias  = (d < DM - 1) ? b_conv[oo] : b_left[0];
    float g[18];
    #pragma unroll
    for (int off = 0; off < 18; ++off)
        g[off] = wrow[(5 - off / 3) * 3 + (off % 3)];

    __syncthreads();

    const float* xrow = xs + cc * TROW;
    float* op = out + ((long long)b * S + t0) * DM + d;

    if (tile != 0 && tile != TILES - 1) {
        // interior block: all chunks unmasked
        for (int tt0 = 0; tt0 < TT; tt0 += CHUNK)
            do_chunk(xrow + tt0, g, bias, op + tt0 * DM);
    } else {
        // edge block: per-chunk uniform test, masked scalar path when needed
        for (int tt0 = 0; tt0 < TT; tt0 += CHUNK) {
            const int tc = t0 + tt0;
            const bool edge = (tc < 16) || (tc + CHUNK >= S);
            if (!edge) {
                do_chunk(xrow + tt0, g, bias, op + tt0 * DM);
            } else {
                #pragma unroll
                for (int i = 0; i < CHUNK; ++i) {
                    float p0 = 0.f, p1 = 0.f, p2 = 0.f;
                    #pragma unroll
                    for (int o = 0; o < 18; o += 3) {
                        p0 = fmaf(g[o],     xrow[tt0 + i + o],     p0);
                        p1 = fmaf(g[o + 1], xrow[tt0 + i + o + 1], p1);
                        p2 = fmaf(g[o + 2], xrow[tt0 + i + o + 2], p2);
                    }
                    const int t = tc + i;
                    const float f0 = (t == 0 || t >= 16)     ? 1.f : 0.f;
                    const float f1 = (t >= 15)               ? 1.f : 0.f;
                    const float f2 = (t >= 14 && t != S - 1) ? 1.f : 0.f;
                    op[(tt0 + i) * DM] = bias + f0 * p0 + f1 * p1 + f2 * p2;
                }
            }
        }
    }
}

extern "C" void kernel_launch(void* const* d_in, const int* in_sizes, int n_in,
                              void* d_out, int out_size, void* d_ws, size_t ws_size,
                              hipStream_t stream) {
    const float* x      = (const float*)d_in[0];
    const float* w_conv = (const float*)d_in[1];
    const float* b_conv = (const float*)d_in[2];
    const float* w_left = (const float*)d_in[3];
    const float* b_left = (const float*)d_in[4];
    float* out = (float*)d_out;

    const int B = in_sizes[0] / (S * CIN);   // 32
    dim3 grid(B * TILES);
    tokemb_kernel<<<grid, 512, 0, stream>>>(x, w_conv, b_conv, w_left, b_left, out);
}